// Round 1
// baseline (587.499 us; speedup 1.0000x reference)
//
#include <hip/hip_runtime.h>

static constexpr int DIN = 128;
static constexpr int HID = 64;

// ===========================================================================
// CSR build: counting sort of edges by dst (proven code).
// After placement, cur[n] == end offset of node n; start(n) = cur[n-1].
// ===========================================================================
__global__ __launch_bounds__(256) void hist_kernel(const int* __restrict__ dst,
                                                   int* __restrict__ cnt, int nE) {
    int i = blockIdx.x * blockDim.x + threadIdx.x;
    if (i < nE) atomicAdd(&cnt[dst[i]], 1);
}

__global__ __launch_bounds__(1024) void scan1_kernel(const int* __restrict__ cnt,
                                                     int* __restrict__ cur,
                                                     int* __restrict__ bsum, int N) {
    __shared__ int s[1024];
    int gid = blockIdx.x * 1024 + threadIdx.x;
    int v = (gid < N) ? cnt[gid] : 0;
    s[threadIdx.x] = v;
    __syncthreads();
    for (int o = 1; o < 1024; o <<= 1) {
        int t = (threadIdx.x >= o) ? s[threadIdx.x - o] : 0;
        __syncthreads();
        s[threadIdx.x] += t;
        __syncthreads();
    }
    if (gid < N) cur[gid] = s[threadIdx.x] - v;
    if (threadIdx.x == 1023) bsum[blockIdx.x] = s[1023];
}

__global__ __launch_bounds__(1024) void scan2_kernel(int* __restrict__ bsum, int nb) {
    __shared__ int s[1024];
    int v = (threadIdx.x < nb) ? bsum[threadIdx.x] : 0;
    s[threadIdx.x] = v;
    __syncthreads();
    for (int o = 1; o < 1024; o <<= 1) {
        int t = (threadIdx.x >= o) ? s[threadIdx.x - o] : 0;
        __syncthreads();
        s[threadIdx.x] += t;
        __syncthreads();
    }
    if (threadIdx.x < nb) bsum[threadIdx.x] = s[threadIdx.x] - v;
}

__global__ __launch_bounds__(1024) void scan3_kernel(int* __restrict__ cur,
                                                     const int* __restrict__ bsum, int N) {
    int gid = blockIdx.x * 1024 + threadIdx.x;
    if (gid < N) cur[gid] += bsum[blockIdx.x];
}

__global__ __launch_bounds__(256) void place_kernel(const int* __restrict__ src,
                                                    const int* __restrict__ dst,
                                                    int* __restrict__ cur,
                                                    int* __restrict__ col, int nE) {
    int i = blockIdx.x * blockDim.x + threadIdx.x;
    if (i < nE) {
        int p = atomicAdd(&cur[dst[i]], 1);
        col[p] = src[i];
    }
}

// ===========================================================================
// proj_dual<K>: Pa[n,j] = sum_k x[n,k]*Wa[k,j]; Pb[n,j] = sum_k x[n,k]*Wb[k,j]
//
// v2: x operand moved OFF the DS pipe. Previous version was LDS-throughput
// bound (16 broadcast ds_read_b128 per 128 FMAs -> modeled 82 us, measured
// 83 us, VALUBusy 50%). Now each wave loads its own 16 rows x 32-k chunk
// straight from global into 8 VGPRs (2 coalesced dwordx4) and broadcasts
// scalars with v_readlane (VALU, constant lane index) into SGPR operands of
// the FMAs. Only W stays in LDS (16 KB, stride-1 reads = 2 lanes/bank =
// conflict-free). DS ops per kk-step: 24 -> 8.
//
// In-place safety (Pb == x for layer 2): each wave reads ONLY its own 16
// rows (register loads) across all k-chunks before the epilogue writes those
// same rows; no other wave/block ever reads them.
// ===========================================================================
__device__ __forceinline__ float rdlane(float v, int lane) {
    return __int_as_float(__builtin_amdgcn_readlane(__float_as_int(v), lane));
}

template<int K>
__global__ __launch_bounds__(256, 4) void proj_dual(
    const float* __restrict__ x, const float* __restrict__ Wa,
    const float* __restrict__ Wb, float* __restrict__ Pa,
    float* __restrict__ Pb, int N)
{
    constexpr int KC = 32;
    __shared__ float sW[KC * 128];     // 16 KB: [kk][0:64]=Wa, [64:128]=Wb
    const int tid  = threadIdx.x;
    const int base = blockIdx.x * 64;
    const int j    = tid & 63;         // lane = output column
    const int wv   = tid >> 6;
    const int R0   = base + wv * 16;   // first row owned by this wave

    float acc[16][2];
    #pragma unroll
    for (int i = 0; i < 16; ++i) { acc[i][0] = 0.f; acc[i][1] = 0.f; }

    for (int k0 = 0; k0 < K; k0 += KC) {
        __syncthreads();   // protect sW readers of the previous chunk
        // ---- stage W chunk to LDS (float4, both mats; 4 float4 per thread) --
        for (int e = tid; e < 2 * KC * 16; e += 256) {
            int m = e >> 9;             // 0 = Wa, 1 = Wb
            int r = (e & 511) >> 4;     // kk within chunk
            int c = (e & 15) << 2;      // column*4
            const float* Wsrc = m ? Wb : Wa;
            float4 u = *(const float4*)&Wsrc[(k0 + r) * 64 + c];
            *(float4*)&sW[r * 128 + m * 64 + c] = u;
        }
        // ---- this wave's 16 rows x KC chunk -> registers (coalesced) -------
        // lane l holds x[R0 + q*8 + (l>>3)][k0 + (l&7)*4 .. +3] in vx{q}
        float4 vx0 = make_float4(0.f, 0.f, 0.f, 0.f);
        float4 vx1 = make_float4(0.f, 0.f, 0.f, 0.f);
        {
            const int r0 = j >> 3;      // 0..7
            const int qd = j & 7;       // k-quad 0..7
            const int n0 = R0 + r0;
            const int n1 = R0 + 8 + r0;
            if (n0 < N) vx0 = *(const float4*)&x[(long long)n0 * K + k0 + qd * 4];
            if (n1 < N) vx1 = *(const float4*)&x[(long long)n1 * K + k0 + qd * 4];
        }
        __syncthreads();

        #pragma unroll
        for (int kk = 0; kk < KC; kk += 4) {
            const int qd = kk >> 2;
            float wa[4], wb[4];
            #pragma unroll
            for (int q = 0; q < 4; ++q) {
                wa[q] = sW[(kk + q) * 128 + j];
                wb[q] = sW[(kk + q) * 128 + 64 + j];
            }
            #pragma unroll
            for (int i = 0; i < 16; ++i) {
                const int sl = ((i & 7) << 3) | qd;    // compile-time constant
                const float4 v = (i < 8) ? vx0 : vx1;  // compile-time select
                const float s0 = rdlane(v.x, sl);
                const float s1 = rdlane(v.y, sl);
                const float s2 = rdlane(v.z, sl);
                const float s3 = rdlane(v.w, sl);
                acc[i][0] = fmaf(s0, wa[0], fmaf(s1, wa[1],
                            fmaf(s2, wa[2], fmaf(s3, wa[3], acc[i][0]))));
                acc[i][1] = fmaf(s0, wb[0], fmaf(s1, wb[1],
                            fmaf(s2, wb[2], fmaf(s3, wb[3], acc[i][1]))));
            }
        }
    }

    #pragma unroll
    for (int i = 0; i < 16; ++i) {
        int n = R0 + i;
        if (n < N) {
            Pa[(long long)n * 64 + j] = acc[i][0];
            Pb[(long long)n * 64 + j] = acc[i][1];
        }
    }
}

// ===========================================================================
// gather_comb: out[n,:] += mean_{e in CSR(n)} P[col[e],:] + bias[:]
//   out already holds the self-term (x_dst @ Wr) written by proj_dual.
//   No LDS, low VGPR -> high occupancy. Wave = 4 node chains; lane group
//   (lane>>4) owns one node; 16 lanes x float4 cover the 256B P-row.
// ===========================================================================
__global__ __launch_bounds__(256) void gather_comb(
    const float* __restrict__ P, const int* __restrict__ ends,
    const int* __restrict__ col, const float* __restrict__ bias,
    float* __restrict__ out, int N)
{
    const int lane = threadIdx.x & 63;
    const int wid  = (blockIdx.x * 256 + threadIdx.x) >> 6;
    const int n    = wid * 4 + (lane >> 4);
    const int c0   = (lane & 15) << 2;
    if (n >= N) return;

    int e        = (n == 0) ? 0 : ends[n - 1];
    const int e1 = ends[n];
    const int deg = e1 - e;

    float4 acc = make_float4(0.f, 0.f, 0.f, 0.f);
    while (e + 2 <= e1) {
        int s0 = col[e], s1 = col[e + 1];
        const float4 v0 = *(const float4*)&P[(long long)s0 * 64 + c0];
        const float4 v1 = *(const float4*)&P[(long long)s1 * 64 + c0];
        acc.x += v0.x + v1.x; acc.y += v0.y + v1.y;
        acc.z += v0.z + v1.z; acc.w += v0.w + v1.w;
        e += 2;
    }
    if (e < e1) {
        const float4 v0 = *(const float4*)&P[(long long)col[e] * 64 + c0];
        acc.x += v0.x; acc.y += v0.y; acc.z += v0.z; acc.w += v0.w;
    }
    const float inv = (deg > 0) ? 1.0f / (float)deg : 0.0f;
    const float4 b4 = *(const float4*)&bias[c0];
    float4 cur = *(float4*)&out[(long long)n * 64 + c0];
    cur.x += acc.x * inv + b4.x;
    cur.y += acc.y * inv + b4.y;
    cur.z += acc.z * inv + b4.z;
    cur.w += acc.w * inv + b4.w;
    *(float4*)&out[(long long)n * 64 + c0] = cur;
}

extern "C" void kernel_launch(void* const* d_in, const int* in_sizes, int n_in,
                              void* d_out, int out_size, void* d_ws, size_t ws_size,
                              hipStream_t stream) {
    const float* x_d    = (const float*)d_in[0];
    const float* x_g    = (const float*)d_in[1];
    const int* src_dg   = (const int*)d_in[2];
    const int* dst_dg   = (const int*)d_in[3];
    const int* src_gd   = (const int*)d_in[4];
    const int* dst_gd   = (const int*)d_in[5];
    const float* Wl1_dg = (const float*)d_in[6];
    const float* bl1_dg = (const float*)d_in[7];
    const float* Wr1_dg = (const float*)d_in[8];
    const float* Wl1_gd = (const float*)d_in[9];
    const float* bl1_gd = (const float*)d_in[10];
    const float* Wr1_gd = (const float*)d_in[11];
    const float* Wl2_dg = (const float*)d_in[12];
    const float* bl2_dg = (const float*)d_in[13];
    const float* Wr2_dg = (const float*)d_in[14];
    const float* Wl2_gd = (const float*)d_in[15];
    const float* bl2_gd = (const float*)d_in[16];
    const float* Wr2_gd = (const float*)d_in[17];

    const int nd = in_sizes[0] / DIN;   // 50000
    const int ng = in_sizes[1] / DIN;   // 100000
    const int ne = in_sizes[2];         // 600000

    // ---- workspace: ~44 MB (well under proven 77 MB) ----
    float* P_d  = (float*)d_ws;                    // [nd,64] msg-projections
    float* P_g  = P_d + (size_t)nd * HID;          // [ng,64]
    int* endsG  = (int*)(P_g + (size_t)ng * HID);  // [ng] CSR(d->g) ends
    int* endsD  = endsG + ng;                      // [nd] CSR(g->d) ends
    int* colG   = endsD + nd;                      // [ne]
    int* colD   = colG + ne;                       // [ne]
    int* cntG   = colD + ne;                       // [ng] scratch
    int* cntD   = cntG + ng;                       // [nd] scratch
    int* bsum   = cntD + nd;                       // [1024]

    // d1/g1 live in the final output regions; proj2 overwrites them in place.
    float* out  = (float*)d_out;
    float* d1r  = out;                             // [nd,64] -> becomes d2
    float* g1r  = out + (size_t)nd * HID;          // [ng,64] -> becomes g2

    const int gE256 = (ne + 255) / 256;
    const int nbG   = (ng + 1023) / 1024;
    const int nbD   = (nd + 1023) / 1024;
    const int gN_g  = (ng + 63) / 64;
    const int gN_d  = (nd + 63) / 64;
    const int gG_g  = (ng + 15) / 16;
    const int gG_d  = (nd + 15) / 16;

    // ---- CSR build, both directions (edge lists shared by both layers) ----
    hipMemsetAsync(cntG, 0, (size_t)(ng + nd) * sizeof(int), stream);

    hist_kernel<<<gE256, 256, 0, stream>>>(dst_dg, cntG, ne);
    scan1_kernel<<<nbG, 1024, 0, stream>>>(cntG, endsG, bsum, ng);
    scan2_kernel<<<1, 1024, 0, stream>>>(bsum, nbG);
    scan3_kernel<<<nbG, 1024, 0, stream>>>(endsG, bsum, ng);
    place_kernel<<<gE256, 256, 0, stream>>>(src_dg, dst_dg, endsG, colG, ne);

    hist_kernel<<<gE256, 256, 0, stream>>>(dst_gd, cntD, ne);
    scan1_kernel<<<nbD, 1024, 0, stream>>>(cntD, endsD, bsum, nd);
    scan2_kernel<<<1, 1024, 0, stream>>>(bsum, nbD);
    scan3_kernel<<<nbD, 1024, 0, stream>>>(endsD, bsum, nd);
    place_kernel<<<gE256, 256, 0, stream>>>(src_gd, dst_gd, endsD, colD, ne);

    // ---- layer 1: dual projections (x read once each) ----
    // x_d -> msg-proj for genes (Wl1_dg) + self-term of d1 (Wr1_gd)
    proj_dual<DIN><<<gN_d, 256, 0, stream>>>(x_d, Wl1_dg, Wr1_gd, P_d, d1r, nd);
    // x_g -> msg-proj for diseases (Wl1_gd) + self-term of g1 (Wr1_dg)
    proj_dual<DIN><<<gN_g, 256, 0, stream>>>(x_g, Wl1_gd, Wr1_dg, P_g, g1r, ng);

    gather_comb<<<gG_g, 256, 0, stream>>>(P_d, endsG, colG, bl1_dg, g1r, ng);  // g1
    gather_comb<<<gG_d, 256, 0, stream>>>(P_g, endsD, colD, bl1_gd, d1r, nd);  // d1

    // ---- layer 2: dual projections, self-term written in place ----
    // g1 -> msg-proj for d2 (Wl2_gd) + self-term of g2 (Wr2_dg, in place)
    proj_dual<HID><<<gN_g, 256, 0, stream>>>(g1r, Wl2_gd, Wr2_dg, P_g, g1r, ng);
    // d1 -> msg-proj for g2 (Wl2_dg) + self-term of d2 (Wr2_gd, in place)
    proj_dual<HID><<<gN_d, 256, 0, stream>>>(d1r, Wl2_dg, Wr2_gd, P_d, d1r, nd);

    gather_comb<<<gG_d, 256, 0, stream>>>(P_g, endsD, colD, bl2_gd, d1r, nd);  // d2
    gather_comb<<<gG_g, 256, 0, stream>>>(P_d, endsG, colG, bl2_dg, g1r, ng);  // g2
}

// Round 2
// 459.541 us; speedup vs baseline: 1.2784x; 1.2784x over previous
//
#include <hip/hip_runtime.h>

static constexpr int DIN = 128;
static constexpr int HID = 64;

typedef short bf16x8 __attribute__((ext_vector_type(8)));
typedef float f32x4  __attribute__((ext_vector_type(4)));

// bf16 helpers (manual RNE, no header dependence)
__device__ __forceinline__ short f2bf(float f) {
    unsigned u = __float_as_uint(f);
    unsigned r = (u + 0x7fff + ((u >> 16) & 1)) >> 16;
    return (short)r;
}
__device__ __forceinline__ float bf2f(short s) {
    return __uint_as_float(((unsigned)(unsigned short)s) << 16);
}

// ===========================================================================
// CSR build: counting sort of edges by dst (proven code).
// ===========================================================================
__global__ __launch_bounds__(256) void hist_kernel(const int* __restrict__ dst,
                                                   int* __restrict__ cnt, int nE) {
    int i = blockIdx.x * blockDim.x + threadIdx.x;
    if (i < nE) atomicAdd(&cnt[dst[i]], 1);
}

__global__ __launch_bounds__(1024) void scan1_kernel(const int* __restrict__ cnt,
                                                     int* __restrict__ cur,
                                                     int* __restrict__ bsum, int N) {
    __shared__ int s[1024];
    int gid = blockIdx.x * 1024 + threadIdx.x;
    int v = (gid < N) ? cnt[gid] : 0;
    s[threadIdx.x] = v;
    __syncthreads();
    for (int o = 1; o < 1024; o <<= 1) {
        int t = (threadIdx.x >= o) ? s[threadIdx.x - o] : 0;
        __syncthreads();
        s[threadIdx.x] += t;
        __syncthreads();
    }
    if (gid < N) cur[gid] = s[threadIdx.x] - v;
    if (threadIdx.x == 1023) bsum[blockIdx.x] = s[1023];
}

__global__ __launch_bounds__(1024) void scan2_kernel(int* __restrict__ bsum, int nb) {
    __shared__ int s[1024];
    int v = (threadIdx.x < nb) ? bsum[threadIdx.x] : 0;
    s[threadIdx.x] = v;
    __syncthreads();
    for (int o = 1; o < 1024; o <<= 1) {
        int t = (threadIdx.x >= o) ? s[threadIdx.x - o] : 0;
        __syncthreads();
        s[threadIdx.x] += t;
        __syncthreads();
    }
    if (threadIdx.x < nb) bsum[threadIdx.x] = s[threadIdx.x] - v;
}

__global__ __launch_bounds__(1024) void scan3_kernel(int* __restrict__ cur,
                                                     const int* __restrict__ bsum, int N) {
    int gid = blockIdx.x * 1024 + threadIdx.x;
    if (gid < N) cur[gid] += bsum[blockIdx.x];
}

__global__ __launch_bounds__(256) void place_kernel(const int* __restrict__ src,
                                                    const int* __restrict__ dst,
                                                    int* __restrict__ cur,
                                                    int* __restrict__ col, int nE) {
    int i = blockIdx.x * blockDim.x + threadIdx.x;
    if (i < nE) {
        int p = atomicAdd(&cur[dst[i]], 1);
        col[p] = src[i];
    }
}

// ===========================================================================
// pack_w: convert the 4 (Wa|Wb) weight pairs into bf16 hi/lo B-fragment
// order for mfma_f32_16x16x32_bf16. Fragment f = ks*8 + cf covers
// k in [ks*32, ks*32+32), cols [cf*16, cf*16+16). Within a fragment,
// lane l / elem i maps to  k = ks*32 + (l>>4)*8 + i,  col = cf*16 + (l&15).
// Layout: out[f*512 + l*8 + i]  -> proj loads one dwordx4 per (frag, lane).
// The (l>>4, i) -> k map only has to MATCH the A-side load order (it does);
// dot-products over k are permutation-invariant.
// ===========================================================================
struct PackW {
    const float* Wa[4]; const float* Wb[4];
    short* oh[4]; short* ol[4];
    int K[4];
};

__global__ __launch_bounds__(256) void pack_w(PackW p) {
    const int c = blockIdx.y;
    const int K = p.K[c];
    const int t = blockIdx.x * 256 + threadIdx.x;   // t = f*64 + l
    if (t >= K * 16) return;                        // (K/32)*8 frags * 64 lanes
    const int f  = t >> 6, l = t & 63;
    const int ks = f >> 3, cf = f & 7;
    const int col = cf * 16 + (l & 15);
    const int kb  = ks * 32 + ((l >> 4) * 8);
    const float* s = (col < 64) ? (p.Wa[c] + col) : (p.Wb[c] + (col - 64));
    short* oh = p.oh[c] + (size_t)t * 8;
    short* ol = p.ol[c] + (size_t)t * 8;
    #pragma unroll
    for (int i = 0; i < 8; ++i) {
        float v = s[(kb + i) * 64];
        short h = f2bf(v);
        oh[i] = h;
        ol[i] = f2bf(v - bf2f(h));
    }
}

// ===========================================================================
// proj_mfma<K>: P[n, 0:128] = x[n, 0:K] @ (Wa|Wb)  via bf16-split MFMA.
//   x = xh + xl, W = wh + wl (bf16 hi + bf16 residual);
//   acc += xh*wh + xh*wl + xl*wh  (fp32 accumulate; dropped xl*wl ~ 2^-16 rel).
// Block = 128 rows, 4 waves x 32 rows (2 row-frags). No LDS: W fragments are
// pre-packed (coalesced 16B/lane loads, L1/L2-resident: 64 KB total), x rows
// read directly (wave reads 16 rows x 128 B contiguous per frag -> coalesced).
// In-place safety (Pb == x, layer 2): a block reads only its own 128 rows,
// all reads precede the epilogue stores of those same rows.
// A-frag: lane l = row (l&15), k = ks*32 + (l>>4)*8 + i   (matches pack_w)
// C/D   : col = cf*16 + (l&15), row = rf*16 + (l>>4)*4 + q [HW-verified m89]
// ===========================================================================
template<int K>
__global__ __launch_bounds__(256) void proj_mfma(
    const float* __restrict__ x, const short* __restrict__ WH,
    const short* __restrict__ WL, float* __restrict__ Pa,
    float* __restrict__ Pb, int N)
{
    const int tid = threadIdx.x;
    const int l   = tid & 63;
    const int w   = tid >> 6;
    const int lr  = l & 15;        // A row / B,D col within fragment
    const int lg  = l >> 4;        // k-group (A) / row-group (D)
    const int r0  = blockIdx.x * 128 + w * 32;

    f32x4 acc[2][8];
    #pragma unroll
    for (int a = 0; a < 2; ++a)
        #pragma unroll
        for (int b = 0; b < 8; ++b)
            acc[a][b] = (f32x4){0.f, 0.f, 0.f, 0.f};

    for (int ks = 0; ks < K / 32; ++ks) {
        // ---- A fragments: 2 row-frags, split into hi/lo bf16 ----
        bf16x8 ah[2], al[2];
        #pragma unroll
        for (int rf = 0; rf < 2; ++rf) {
            const int row = r0 + rf * 16 + lr;
            float4 u0 = make_float4(0.f, 0.f, 0.f, 0.f);
            float4 u1 = make_float4(0.f, 0.f, 0.f, 0.f);
            if (row < N) {
                const float* p = &x[(long long)row * K + ks * 32 + lg * 8];
                u0 = *(const float4*)p;
                u1 = *(const float4*)(p + 4);
            }
            const float vv[8] = {u0.x, u0.y, u0.z, u0.w, u1.x, u1.y, u1.z, u1.w};
            #pragma unroll
            for (int i = 0; i < 8; ++i) {
                short h = f2bf(vv[i]);
                ah[rf][i] = h;
                al[rf][i] = f2bf(vv[i] - bf2f(h));
            }
        }
        // ---- B fragments (pre-packed) + 3-term MFMA ----
        const short* wb = WH + (size_t)(ks * 8) * 512;
        const short* lb = WL + (size_t)(ks * 8) * 512;
        #pragma unroll
        for (int cf = 0; cf < 8; ++cf) {
            const bf16x8 bh = *(const bf16x8*)(wb + cf * 512 + l * 8);
            const bf16x8 bl = *(const bf16x8*)(lb + cf * 512 + l * 8);
            #pragma unroll
            for (int rf = 0; rf < 2; ++rf) {
                acc[rf][cf] = __builtin_amdgcn_mfma_f32_16x16x32_bf16(ah[rf], bh, acc[rf][cf], 0, 0, 0);
                acc[rf][cf] = __builtin_amdgcn_mfma_f32_16x16x32_bf16(ah[rf], bl, acc[rf][cf], 0, 0, 0);
                acc[rf][cf] = __builtin_amdgcn_mfma_f32_16x16x32_bf16(al[rf], bh, acc[rf][cf], 0, 0, 0);
            }
        }
    }

    // ---- epilogue: D row = rf*16 + lg*4 + q, col = cf*16 + lr ----
    #pragma unroll
    for (int rf = 0; rf < 2; ++rf) {
        #pragma unroll
        for (int q = 0; q < 4; ++q) {
            const int row = r0 + rf * 16 + lg * 4 + q;
            if (row < N) {
                #pragma unroll
                for (int cf = 0; cf < 8; ++cf) {
                    const float v = acc[rf][cf][q];
                    if (cf < 4) Pa[(long long)row * 64 + cf * 16 + lr] = v;
                    else        Pb[(long long)row * 64 + (cf - 4) * 16 + lr] = v;
                }
            }
        }
    }
}

// ===========================================================================
// gather_comb: out[n,:] += mean_{e in CSR(n)} P[col[e],:] + bias[:]
//   (proven code, unchanged)
// ===========================================================================
__global__ __launch_bounds__(256) void gather_comb(
    const float* __restrict__ P, const int* __restrict__ ends,
    const int* __restrict__ col, const float* __restrict__ bias,
    float* __restrict__ out, int N)
{
    const int lane = threadIdx.x & 63;
    const int wid  = (blockIdx.x * 256 + threadIdx.x) >> 6;
    const int n    = wid * 4 + (lane >> 4);
    const int c0   = (lane & 15) << 2;
    if (n >= N) return;

    int e        = (n == 0) ? 0 : ends[n - 1];
    const int e1 = ends[n];
    const int deg = e1 - e;

    float4 acc = make_float4(0.f, 0.f, 0.f, 0.f);
    while (e + 2 <= e1) {
        int s0 = col[e], s1 = col[e + 1];
        const float4 v0 = *(const float4*)&P[(long long)s0 * 64 + c0];
        const float4 v1 = *(const float4*)&P[(long long)s1 * 64 + c0];
        acc.x += v0.x + v1.x; acc.y += v0.y + v1.y;
        acc.z += v0.z + v1.z; acc.w += v0.w + v1.w;
        e += 2;
    }
    if (e < e1) {
        const float4 v0 = *(const float4*)&P[(long long)col[e] * 64 + c0];
        acc.x += v0.x; acc.y += v0.y; acc.z += v0.z; acc.w += v0.w;
    }
    const float inv = (deg > 0) ? 1.0f / (float)deg : 0.0f;
    const float4 b4 = *(const float4*)&bias[c0];
    float4 cur = *(float4*)&out[(long long)n * 64 + c0];
    cur.x += acc.x * inv + b4.x;
    cur.y += acc.y * inv + b4.y;
    cur.z += acc.z * inv + b4.z;
    cur.w += acc.w * inv + b4.w;
    *(float4*)&out[(long long)n * 64 + c0] = cur;
}

extern "C" void kernel_launch(void* const* d_in, const int* in_sizes, int n_in,
                              void* d_out, int out_size, void* d_ws, size_t ws_size,
                              hipStream_t stream) {
    const float* x_d    = (const float*)d_in[0];
    const float* x_g    = (const float*)d_in[1];
    const int* src_dg   = (const int*)d_in[2];
    const int* dst_dg   = (const int*)d_in[3];
    const int* src_gd   = (const int*)d_in[4];
    const int* dst_gd   = (const int*)d_in[5];
    const float* Wl1_dg = (const float*)d_in[6];
    const float* bl1_dg = (const float*)d_in[7];
    const float* Wr1_dg = (const float*)d_in[8];
    const float* Wl1_gd = (const float*)d_in[9];
    const float* bl1_gd = (const float*)d_in[10];
    const float* Wr1_gd = (const float*)d_in[11];
    const float* Wl2_dg = (const float*)d_in[12];
    const float* bl2_dg = (const float*)d_in[13];
    const float* Wr2_dg = (const float*)d_in[14];
    const float* Wl2_gd = (const float*)d_in[15];
    const float* bl2_gd = (const float*)d_in[16];
    const float* Wr2_gd = (const float*)d_in[17];

    const int nd = in_sizes[0] / DIN;   // 50000
    const int ng = in_sizes[1] / DIN;   // 100000
    const int ne = in_sizes[2];         // 600000

    // ---- workspace ----
    float* P_d  = (float*)d_ws;                    // [nd,64]
    float* P_g  = P_d + (size_t)nd * HID;          // [ng,64]
    int* endsG  = (int*)(P_g + (size_t)ng * HID);  // [ng]
    int* endsD  = endsG + ng;                      // [nd]
    int* colG   = endsD + nd;                      // [ne]
    int* colD   = colG + ne;                       // [ne]
    int* cntG   = colD + ne;                       // [ng]
    int* cntD   = cntG + ng;                       // [nd]
    int* bsum   = cntD + nd;                       // [1024]

    // packed bf16 hi/lo weight fragments (16B aligned)
    uintptr_t wp = (uintptr_t)(bsum + 1024);
    wp = (wp + 63) & ~(uintptr_t)63;
    short* wh0 = (short*)wp;        // K=128: 32 frags * 512 = 16384 shorts
    short* wl0 = wh0 + 16384;
    short* wh1 = wl0 + 16384;
    short* wl1 = wh1 + 16384;
    short* wh2 = wl1 + 16384;       // K=64: 16 frags * 512 = 8192
    short* wl2 = wh2 + 8192;
    short* wh3 = wl2 + 8192;
    short* wl3 = wh3 + 8192;

    float* out  = (float*)d_out;
    float* d1r  = out;                             // [nd,64] -> becomes d2
    float* g1r  = out + (size_t)nd * HID;          // [ng,64] -> becomes g2

    const int gE256 = (ne + 255) / 256;
    const int nbG   = (ng + 1023) / 1024;
    const int nbD   = (nd + 1023) / 1024;
    const int gM_g  = (ng + 127) / 128;
    const int gM_d  = (nd + 127) / 128;
    const int gG_g  = (ng + 15) / 16;
    const int gG_d  = (nd + 15) / 16;

    // ---- weight packing (once, tiny) ----
    PackW pw;
    pw.Wa[0] = Wl1_dg; pw.Wb[0] = Wr1_gd; pw.oh[0] = wh0; pw.ol[0] = wl0; pw.K[0] = 128;
    pw.Wa[1] = Wl1_gd; pw.Wb[1] = Wr1_dg; pw.oh[1] = wh1; pw.ol[1] = wl1; pw.K[1] = 128;
    pw.Wa[2] = Wl2_gd; pw.Wb[2] = Wr2_dg; pw.oh[2] = wh2; pw.ol[2] = wl2; pw.K[2] = 64;
    pw.Wa[3] = Wl2_dg; pw.Wb[3] = Wr2_gd; pw.oh[3] = wh3; pw.ol[3] = wl3; pw.K[3] = 64;
    pack_w<<<dim3(8, 4), 256, 0, stream>>>(pw);

    // ---- CSR build, both directions ----
    hipMemsetAsync(cntG, 0, (size_t)(ng + nd) * sizeof(int), stream);

    hist_kernel<<<gE256, 256, 0, stream>>>(dst_dg, cntG, ne);
    scan1_kernel<<<nbG, 1024, 0, stream>>>(cntG, endsG, bsum, ng);
    scan2_kernel<<<1, 1024, 0, stream>>>(bsum, nbG);
    scan3_kernel<<<nbG, 1024, 0, stream>>>(endsG, bsum, ng);
    place_kernel<<<gE256, 256, 0, stream>>>(src_dg, dst_dg, endsG, colG, ne);

    hist_kernel<<<gE256, 256, 0, stream>>>(dst_gd, cntD, ne);
    scan1_kernel<<<nbD, 1024, 0, stream>>>(cntD, endsD, bsum, nd);
    scan2_kernel<<<1, 1024, 0, stream>>>(bsum, nbD);
    scan3_kernel<<<nbD, 1024, 0, stream>>>(endsD, bsum, nd);
    place_kernel<<<gE256, 256, 0, stream>>>(src_gd, dst_gd, endsD, colD, ne);

    // ---- layer 1 ----
    proj_mfma<DIN><<<gM_d, 256, 0, stream>>>(x_d, wh0, wl0, P_d, d1r, nd);
    proj_mfma<DIN><<<gM_g, 256, 0, stream>>>(x_g, wh1, wl1, P_g, g1r, ng);

    gather_comb<<<gG_g, 256, 0, stream>>>(P_d, endsG, colG, bl1_dg, g1r, ng);  // g1
    gather_comb<<<gG_d, 256, 0, stream>>>(P_g, endsD, colD, bl1_gd, d1r, nd);  // d1

    // ---- layer 2 (self-term written in place) ----
    proj_mfma<HID><<<gM_g, 256, 0, stream>>>(g1r, wh2, wl2, P_g, g1r, ng);
    proj_mfma<HID><<<gM_d, 256, 0, stream>>>(d1r, wh3, wl3, P_d, d1r, nd);

    gather_comb<<<gG_d, 256, 0, stream>>>(P_g, endsD, colD, bl2_gd, d1r, nd);  // d2
    gather_comb<<<gG_g, 256, 0, stream>>>(P_d, endsG, colG, bl2_dg, g1r, ng);  // g2
}